// Round 13
// baseline (1388.575 us; speedup 1.0000x reference)
//
#include <hip/hip_runtime.h>

typedef unsigned short u16;
typedef unsigned int u32;
typedef __attribute__((ext_vector_type(8))) __bf16 bf16x8;
typedef __attribute__((ext_vector_type(4))) float f32x4;
typedef __attribute__((ext_vector_type(4))) u32 u32x4;

#define ASYNC16(g, l) __builtin_amdgcn_global_load_lds( \
    (const __attribute__((address_space(1))) unsigned int*)(g), \
    (__attribute__((address_space(3))) unsigned int*)(l), 16, 0, 0)

__device__ __forceinline__ u16 f2bf(float f){
  unsigned u = __float_as_uint(f);
  unsigned r = u + 0x7fffu + ((u >> 16) & 1u);
  return (u16)(r >> 16);
}

// ---------------- fp32 -> bf16 conversion ----------------
__global__ __launch_bounds__(256) void f2bf_kernel(const float* __restrict__ in,
                                                   u16* __restrict__ out, int n){
  int i = (blockIdx.x * 256 + threadIdx.x) * 8;
  if (i >= n) return;
  float4 a = *(const float4*)&in[i];
  float4 b = *(const float4*)&in[i + 4];
  u16 r[8] = {f2bf(a.x), f2bf(a.y), f2bf(a.z), f2bf(a.w),
              f2bf(b.x), f2bf(b.y), f2bf(b.z), f2bf(b.w)};
  *(uint4*)&out[i] = *(const uint4*)r;
}

// ---------------- ctx projections: ses_inf, h0 ----------------
__global__ __launch_bounds__(256) void ctx_kernel(const float* __restrict__ ctx,
    const float* __restrict__ Wses, const float* __restrict__ Ws2d,
    const float* __restrict__ bs2d, float* __restrict__ sesinf,
    float* __restrict__ h0f, u16* __restrict__ h0bf){
  int id = blockIdx.x * 4 + (threadIdx.x >> 6);
  int lane = threadIdx.x & 63;
  int n = id & 1023, b = (id >> 10) & 15, mat = id >> 14;
  const float* w = (mat ? Ws2d : Wses) + (size_t)n * 1024;
  const float* x = ctx + (size_t)b * 1024;
  float v = 0.f;
  #pragma unroll 4
  for (int k = lane; k < 1024; k += 64) v += x[k] * w[k];
  #pragma unroll
  for (int off = 32; off; off >>= 1) v += __shfl_down(v, off);
  if (lane == 0){
    if (mat == 0) sesinf[b * 1024 + n] = v;
    else {
      float t = tanhf(v + bs2d[n]);
      h0f[b * 1024 + n] = t;
      h0bf[b * 1024 + n] = f2bf(t);
    }
  }
}

// ---------------- embedding gather (bf16 rows) ----------------
__global__ void gather_kernel(const int* __restrict__ target,
                              const u16* __restrict__ embedBF, u16* __restrict__ embBF){
  int i = blockIdx.x;
  int t = target[i];
  int lane = threadIdx.x;
  *(uint4*)&embBF[(size_t)i * 512 + lane * 8] =
      *(const uint4*)&embedBF[(size_t)t * 512 + lane * 8];
}

// ---------------- bf16 GEMM: C[M][N] = A[M][K] * B[N][K]^T (+epilogue) ----------------
// SWZ: bijective XCD-aware wgid remap (requires nwg % 8 == 0)
// EPI: 0=none, 1=+bias[col], 2=+add0+add1 -> C, 3=+add0+add1 -> pairwise-max -> bf16 mxout
template<int EPI, int SWZ>
__global__ __launch_bounds__(256) void gemm_bt(
    const u16* __restrict__ A, const u16* __restrict__ B, float* __restrict__ C,
    int M, int N, int K,
    const float* __restrict__ bias, const float* __restrict__ add0,
    const float* __restrict__ add1, u16* __restrict__ mxout)
{
  __shared__ u16 sA[2][128 * 32];
  __shared__ u16 sB[2][128 * 32];
  int bx = blockIdx.x, by = blockIdx.y;
  if (SWZ){
    int nwg = gridDim.x * gridDim.y;
    int wg = by * gridDim.x + bx;
    int q = nwg >> 3;
    int nw = (wg & 7) * q + (wg >> 3);
    bx = nw % gridDim.x; by = nw / gridDim.x;
  }
  const int n0 = bx * 128;
  const int m0 = by * 128;
  const int tid = threadIdx.x;
  const int lane = tid & 63;
  const int wid = tid >> 6;
  const int wm = (wid >> 1) * 64, wn = (wid & 1) * 64;
  const int l15 = lane & 15, kg = (lane >> 4) * 8;
  (void)M;

  f32x4 zero = {0.f, 0.f, 0.f, 0.f};
  f32x4 acc[4][4];
  #pragma unroll
  for (int m = 0; m < 4; m++)
    #pragma unroll
    for (int n = 0; n < 4; n++) acc[m][n] = zero;

  auto stage = [&](int buf, int kk){
    const u16* Ab = A + (size_t)m0 * K + kk;
    const u16* Bb = B + (size_t)n0 * K + kk;
    #pragma unroll
    for (int j = 0; j < 2; j++){
      int c = j * 256 + tid;
      ASYNC16(Ab + (size_t)(c >> 2) * K + (c & 3) * 8, &sA[buf][c * 8]);
    }
    #pragma unroll
    for (int j = 0; j < 2; j++){
      int c = j * 256 + tid;
      ASYNC16(Bb + (size_t)(c >> 2) * K + (c & 3) * 8, &sB[buf][c * 8]);
    }
  };

  stage(0, 0);
  int cur = 0;
  for (int kk = 0; kk < K; kk += 32){
    __syncthreads();
    if (kk + 32 < K) stage(cur ^ 1, kk + 32);
    bf16x8 af[4], bf_[4];
    #pragma unroll
    for (int m = 0; m < 4; m++)
      af[m] = *(const bf16x8*)&sA[cur][(wm + m * 16 + l15) * 32 + kg];
    #pragma unroll
    for (int n = 0; n < 4; n++)
      bf_[n] = *(const bf16x8*)&sB[cur][(wn + n * 16 + l15) * 32 + kg];
    #pragma unroll
    for (int m = 0; m < 4; m++)
      #pragma unroll
      for (int n = 0; n < 4; n++)
        acc[m][n] = __builtin_amdgcn_mfma_f32_16x16x32_bf16(af[m], bf_[n], acc[m][n], 0, 0, 0);
    cur ^= 1;
  }

  const int rb = m0 + wm + (lane >> 4) * 4;
  const int cb = n0 + wn + l15;
  #pragma unroll
  for (int m = 0; m < 4; m++){
    #pragma unroll
    for (int n = 0; n < 4; n++){
      #pragma unroll
      for (int i = 0; i < 4; i++){
        int row = rb + m * 16 + i;
        int col = cb + n * 16;
        float v = acc[m][n][i];
        if (EPI == 1) v += bias[col];
        if (EPI == 2 || EPI == 3)
          v += add0[(row >> 8) * N + col] + add1[(size_t)row * N + col];
        if (EPI == 3){
          // pairwise maxout: col pairs (2e,2e+1) live in adjacent lanes
          float w = __shfl_xor(v, 1);
          if ((l15 & 1) == 0)
            mxout[(size_t)row * (N >> 1) + (col >> 1)] = f2bf(fmaxf(v, w));
        } else {
          C[(size_t)row * N + col] = v;
        }
      }
    }
  }
}

// ---------------- persistent GRU (tagged-dword exchange, thin per-thread poll) ----------------
// 64 WGs x 1024 thr (12 MFMA waves, R12 compute structure). NO flags, NO
// drain, NO end-of-step barriers. Exchange = self-validating tagged dwords
// xb[parity][batch][col] = (bf16(h)<<16) | step, published with relaxed
// agent (sc1 write-through) stores, fire-and-forget. Stage = poll-on-data:
// each of 1024 threads owns 2 chunks x 8 cols; per round it loads 2 dwordx4
// per pending chunk, vmcnt(0)+sched_barrier (rule#18), tag-checks ITS OWN
// dwords, de-tags (v_perm) into LDS, retries only stale chunks (<=32B).
// The post-stage __syncthreads gates MFMA (no wave-uniform accept needed --
// R9's overhead). Parity double-buffer overwrite-safe by the R5/R6 step-
// coupling argument; replay-safe: memset per launch + deterministic values.
#define GRU_NWG 64
#define GRU_LDS 145408

__global__ __launch_bounds__(1024) void gru_kernel(
    const u16* __restrict__ WhhBF, const float* __restrict__ bhh,
    const float* __restrict__ xproj, const float* __restrict__ h0f,
    const u16* __restrict__ h0bf, u16* __restrict__ hsBF, u32* __restrict__ xb)
{
  extern __shared__ char smem[];
  u16*  Wl   = (u16*)smem;                 // [48][1032]
  u16*  hb   = Wl + 48 * 1032;             // [16][1032]
  float* gbuf = (float*)(smem + 132096);   // [12][256]  tile: [batch*16+owncol]
  float* hown = gbuf + 12 * 256;           // [16][16]

  const int g = blockIdx.x;
  const int j0 = g * 16;
  const int tid = threadIdx.x;
  const int lane = tid & 63;
  const int wid = tid >> 6;
  const int l15 = lane & 15, kh8 = (lane >> 4) * 8;

  // one-time: W_hh slice -> LDS (rows {j, H+j, 2H+j})
  for (int c = tid; c < 48 * 128; c += 1024){
    int r = c >> 7, cg = (c & 127) * 8;
    int gate = r >> 4, n = r & 15;
    *(uint4*)&Wl[r * 1032 + cg] =
        *(const uint4*)&WhhBF[(size_t)(gate * 1024 + j0 + n) * 1024 + cg];
  }
  // gates-thread setup (tid < 256): batch bb, own col jj
  const int bb = (tid & 255) >> 4, jj = tid & 15;
  float bh0 = 0.f, bh1 = 0.f, bh2 = 0.f;
  if (tid < 256){
    hown[bb * 16 + jj] = h0f[bb * 1024 + j0 + jj];
    bh0 = bhh[j0 + jj];
    bh1 = bhh[1024 + j0 + jj];
    bh2 = bhh[2048 + j0 + jj];
  }
  // stage addressing for this thread's two 8-col chunks
  const int c0 = tid,         b0 = c0 >> 7, cg0 = (c0 & 127) * 8;
  const int c1 = tid + 1024,  b1 = c1 >> 7, cg1 = (c1 & 127) * 8;
  __syncthreads();

  for (int s = 0; s < 256; ++s){
    // ---- stage h_s into LDS ----
    if (s == 0){
      *(uint4*)&hb[b0 * 1032 + cg0] = *(const uint4*)&h0bf[b0 * 1024 + cg0];
      *(uint4*)&hb[b1 * 1032 + cg1] = *(const uint4*)&h0bf[b1 * 1024 + cg1];
    } else {
      const u32* base = xb + ((u32)(s & 1) << 14);
      const u32* p0 = base + b0 * 1024 + cg0;
      const u32* p1 = base + b1 * 1024 + cg1;
      u32 need = 3u;
      u32x4 ta, tb, tc, td;
      while (need){
        if (need & 1u){
          asm volatile("global_load_dwordx4 %0, %1, off sc1"
                       : "=v"(ta) : "v"(p0) : "memory");
          asm volatile("global_load_dwordx4 %0, %1, off sc1"
                       : "=v"(tb) : "v"(p0 + 4) : "memory");
        }
        if (need & 2u){
          asm volatile("global_load_dwordx4 %0, %1, off sc1"
                       : "=v"(tc) : "v"(p1) : "memory");
          asm volatile("global_load_dwordx4 %0, %1, off sc1"
                       : "=v"(td) : "v"(p1 + 4) : "memory");
        }
        asm volatile("s_waitcnt vmcnt(0)" ::: "memory");
        __builtin_amdgcn_sched_barrier(0);   // rule#18: no hoist past waitcnt
        if (need & 1u){
          u32 m = ((ta[0] ^ (u32)s) | (ta[1] ^ (u32)s) |
                   (ta[2] ^ (u32)s) | (ta[3] ^ (u32)s) |
                   (tb[0] ^ (u32)s) | (tb[1] ^ (u32)s) |
                   (tb[2] ^ (u32)s) | (tb[3] ^ (u32)s)) & 0xFFFFu;
          if (m == 0){
            u32 dd[4];
            dd[0] = __builtin_amdgcn_perm(ta[1], ta[0], 0x07060302u);
            dd[1] = __builtin_amdgcn_perm(ta[3], ta[2], 0x07060302u);
            dd[2] = __builtin_amdgcn_perm(tb[1], tb[0], 0x07060302u);
            dd[3] = __builtin_amdgcn_perm(tb[3], tb[2], 0x07060302u);
            *(uint4*)&hb[b0 * 1032 + cg0] = *(const uint4*)dd;
            need &= ~1u;
          }
        }
        if (need & 2u){
          u32 m = ((tc[0] ^ (u32)s) | (tc[1] ^ (u32)s) |
                   (tc[2] ^ (u32)s) | (tc[3] ^ (u32)s) |
                   (td[0] ^ (u32)s) | (td[1] ^ (u32)s) |
                   (td[2] ^ (u32)s) | (td[3] ^ (u32)s)) & 0xFFFFu;
          if (m == 0){
            u32 dd[4];
            dd[0] = __builtin_amdgcn_perm(tc[1], tc[0], 0x07060302u);
            dd[1] = __builtin_amdgcn_perm(tc[3], tc[2], 0x07060302u);
            dd[2] = __builtin_amdgcn_perm(td[1], td[0], 0x07060302u);
            dd[3] = __builtin_amdgcn_perm(td[3], td[2], 0x07060302u);
            *(uint4*)&hb[b1 * 1032 + cg1] = *(const uint4*)dd;
            need &= ~2u;
          }
        }
        if (need) __builtin_amdgcn_s_sleep(1);
      }
    }

    // prefetch this step's x_proj scalars (gates threads only)
    float xr = 0.f, xz = 0.f, xn = 0.f;
    if (tid < 256){
      const float* xp = xproj + ((size_t)(bb << 8) + s) * 3072;
      xr = xp[j0 + jj]; xz = xp[1024 + j0 + jj]; xn = xp[2048 + j0 + jj];
    }
    __syncthreads();

    // ---- MFMA: wave wid<12 = (gate wid>>2, K-quarter wid&3) ----
    if (wid < 12){
      const int gate = wid >> 2, Koff = (wid & 3) * 256;
      f32x4 acc0 = {0.f, 0.f, 0.f, 0.f};
      f32x4 acc1 = {0.f, 0.f, 0.f, 0.f};
      const u16* wrow = &Wl[(gate * 16 + l15) * 1032 + Koff];
      const u16* hrow = &hb[l15 * 1032 + Koff];
      #pragma unroll
      for (int kk = 0; kk < 256; kk += 64){
        bf16x8 a0 = *(const bf16x8*)&hrow[kk + kh8];
        bf16x8 w0 = *(const bf16x8*)&wrow[kk + kh8];
        acc0 = __builtin_amdgcn_mfma_f32_16x16x32_bf16(a0, w0, acc0, 0, 0, 0);
        bf16x8 a1 = *(const bf16x8*)&hrow[kk + 32 + kh8];
        bf16x8 w1 = *(const bf16x8*)&wrow[kk + 32 + kh8];
        acc1 = __builtin_amdgcn_mfma_f32_16x16x32_bf16(a1, w1, acc1, 0, 0, 0);
      }
      #pragma unroll
      for (int i = 0; i < 4; ++i)
        gbuf[wid * 256 + ((lane >> 4) * 4 + i) * 16 + l15] = acc0[i] + acc1[i];
    }
    __syncthreads();

    // ---- gates (tid<256): sum partials; publish tagged dword (no drain) ----
    if (tid < 256){
      int ic = bb * 16 + jj;
      float hr = gbuf[0 * 256 + ic] + gbuf[1 * 256 + ic] +
                 gbuf[2 * 256 + ic] + gbuf[3 * 256 + ic] + bh0;
      float hz = gbuf[4 * 256 + ic] + gbuf[5 * 256 + ic] +
                 gbuf[6 * 256 + ic] + gbuf[7 * 256 + ic] + bh1;
      float hn = gbuf[8 * 256 + ic] + gbuf[9 * 256 + ic] +
                 gbuf[10 * 256 + ic] + gbuf[11 * 256 + ic] + bh2;
      float r = 1.f / (1.f + __expf(-(xr + hr)));
      float z = 1.f / (1.f + __expf(-(xz + hz)));
      float nn = tanhf(xn + r * hn);
      float hnew = (1.f - z) * nn + z * hown[bb * 16 + jj];
      hown[bb * 16 + jj] = hnew;
      u16 hv = f2bf(hnew);
      hsBF[((size_t)(bb << 8) + s) * 1024 + j0 + jj] = hv;  // plain (read post-kernel)
      if (s < 255){
        u32 pack = ((u32)hv << 16) | (u32)(s + 1);
        __hip_atomic_store(&xb[((u32)(((s + 1) & 1)) << 14) + bb * 1024 + j0 + jj],
                           pack, __ATOMIC_RELAXED, __HIP_MEMORY_SCOPE_AGENT);
      }
    }
    // no trailing barrier: hb rewrites next step are post-MFMA-barrier safe;
    // gbuf rewrites gated by the post-stage barrier; cross-WG order by tags.
  }
}

extern "C" void kernel_launch(void* const* d_in, const int* in_sizes, int n_in,
                              void* d_out, int out_size, void* d_ws, size_t ws_size,
                              hipStream_t stream)
{
  const float* ctx    = (const float*)d_in[0];
  const int*   target = (const int*)d_in[1];
  const float* embed  = (const float*)d_in[2];
  const float* Ws2d   = (const float*)d_in[3];
  const float* bs2d   = (const float*)d_in[4];
  const float* Wdec   = (const float*)d_in[5];
  const float* Wses   = (const float*)d_in[6];
  const float* Wemb   = (const float*)d_in[7];
  const float* bemb   = (const float*)d_in[8];
  const float* Wih    = (const float*)d_in[9];
  const float* Whh    = (const float*)d_in[10];
  const float* bih    = (const float*)d_in[11];
  const float* bhh    = (const float*)d_in[12];
  float* out = (float*)d_out;

  char* ws = (char*)d_ws;
  size_t off = 0;
  auto alloc = [&](size_t bytes)->char*{
    char* p = ws + off; off += (bytes + 255) & ~(size_t)255; return p;
  };
  u16*   embedBF = (u16*)alloc(32000ull * 512 * 2);
  u16*   WihBF   = (u16*)alloc(3072ull * 512 * 2);
  u16*   WembBF  = (u16*)alloc(1024ull * 512 * 2);
  u16*   WdecBF  = (u16*)alloc(1024ull * 1024 * 2);
  u16*   WhhBF   = (u16*)alloc(3072ull * 1024 * 2);
  u16*   embBF   = (u16*)alloc(4096ull * 512 * 2);
  float* xproj   = (float*)alloc(4096ull * 3072 * 4);
  float* embinf  = (float*)alloc(4096ull * 1024 * 4);
  float* sesinf  = (float*)alloc(16ull * 1024 * 4);
  float* h0f     = (float*)alloc(16ull * 1024 * 4);
  u16*   h0bf    = (u16*)alloc(16ull * 1024 * 2);
  u16*   hsBF    = (u16*)alloc(4096ull * 1024 * 2);
  u16*   mxBF    = (u16*)alloc(4096ull * 512 * 2);
  u32*   xbuf    = (u32*)alloc(2ull * 16 * 1024 * 4);   // [2][16][1024] tagged dwords
  (void)ws_size; (void)in_sizes; (void)n_in; (void)out_size;

  hipFuncSetAttribute((const void*)gru_kernel,
                      hipFuncAttributeMaxDynamicSharedMemorySize, GRU_LDS);
  hipMemsetAsync(xbuf, 0, 2ull * 16 * 1024 * 4, stream);

  auto conv = [&](const float* in, u16* o, size_t n){
    f2bf_kernel<<<dim3((unsigned)((n / 8 + 255) / 256)), 256, 0, stream>>>(in, o, (int)n);
  };
  conv(embed, embedBF, 32000ull * 512);
  conv(Wih,   WihBF,   3072ull * 512);
  conv(Wemb,  WembBF,  1024ull * 512);
  conv(Wdec,  WdecBF,  1024ull * 1024);
  conv(Whh,   WhhBF,   3072ull * 1024);

  ctx_kernel<<<8192, 256, 0, stream>>>(ctx, Wses, Ws2d, bs2d, sesinf, h0f, h0bf);
  gather_kernel<<<4096, 64, 0, stream>>>(target, embedBF, embBF);

  // x_proj = emb @ W_ih^T + b_ih ; emb_inf = emb @ W_emb^T + b_emb
  gemm_bt<1,0><<<dim3(3072 / 128, 4096 / 128), 256, 0, stream>>>(
      embBF, WihBF, xproj, 4096, 3072, 512, bih, nullptr, nullptr, nullptr);
  gemm_bt<1,0><<<dim3(1024 / 128, 4096 / 128), 256, 0, stream>>>(
      embBF, WembBF, embinf, 4096, 1024, 512, bemb, nullptr, nullptr, nullptr);

  gru_kernel<<<GRU_NWG, 1024, GRU_LDS, stream>>>(WhhBF, bhh, xproj, h0f, h0bf,
                                                 hsBF, xbuf);

  // total = hs @ W_dec^T + ses_inf[b] + emb_inf ; fused pairwise-maxout -> mxBF
  gemm_bt<3,0><<<dim3(1024 / 128, 4096 / 128), 256, 0, stream>>>(
      hsBF, WdecBF, nullptr, 4096, 1024, 1024, nullptr, sesinf, embinf, mxBF);

  // logits = mx @ embed^T  (XCD-swizzled: 8000 WGs % 8 == 0)
  gemm_bt<0,1><<<dim3(32000 / 128, 4096 / 128), 256, 0, stream>>>(
      mxBF, embedBF, out, 4096, 32000, 512, nullptr, nullptr, nullptr, nullptr);
}

// Round 14
// 1200.843 us; speedup vs baseline: 1.1563x; 1.1563x over previous
//
#include <hip/hip_runtime.h>

typedef unsigned short u16;
typedef unsigned int u32;
typedef __attribute__((ext_vector_type(8))) __bf16 bf16x8;
typedef __attribute__((ext_vector_type(4))) float f32x4;
typedef __attribute__((ext_vector_type(4))) u32 u32x4;

#define ASYNC16(g, l) __builtin_amdgcn_global_load_lds( \
    (const __attribute__((address_space(1))) unsigned int*)(g), \
    (__attribute__((address_space(3))) unsigned int*)(l), 16, 0, 0)

__device__ __forceinline__ u16 f2bf(float f){
  unsigned u = __float_as_uint(f);
  unsigned r = u + 0x7fffu + ((u >> 16) & 1u);
  return (u16)(r >> 16);
}
__device__ __forceinline__ float b2f(u16 v){
  return __uint_as_float((u32)v << 16);
}

// ---------------- fused fp32 -> bf16 conversion (all 5 weight tensors) ----------------
// segment cumulative sizes (elements), all 8-divisible:
// embed 16384000 | Wih 1572864 | Wemb 524288 | Wdec 1048576 | Whh 3145728
__global__ __launch_bounds__(256) void conv_all_kernel(
    const float* __restrict__ e, const float* __restrict__ wih,
    const float* __restrict__ wemb, const float* __restrict__ wdec,
    const float* __restrict__ whh,
    u16* __restrict__ oe, u16* __restrict__ oih, u16* __restrict__ oemb,
    u16* __restrict__ odec, u16* __restrict__ ohh)
{
  long i = ((long)blockIdx.x * 256 + threadIdx.x) * 8;   // < 22675456
  const float* src; u16* dst; long off;
  if (i < 16384000L)      { src = e;    dst = oe;   off = i; }
  else if (i < 17956864L) { src = wih;  dst = oih;  off = i - 16384000L; }
  else if (i < 18481152L) { src = wemb; dst = oemb; off = i - 17956864L; }
  else if (i < 19529728L) { src = wdec; dst = odec; off = i - 18481152L; }
  else                    { src = whh;  dst = ohh;  off = i - 19529728L; }
  float4 a = *(const float4*)&src[off];
  float4 b = *(const float4*)&src[off + 4];
  u16 r[8] = {f2bf(a.x), f2bf(a.y), f2bf(a.z), f2bf(a.w),
              f2bf(b.x), f2bf(b.y), f2bf(b.z), f2bf(b.w)};
  *(uint4*)&dst[off] = *(const uint4*)r;
}

// ---------------- ctx projections: ses_inf, h0 ----------------
__global__ __launch_bounds__(256) void ctx_kernel(const float* __restrict__ ctx,
    const float* __restrict__ Wses, const float* __restrict__ Ws2d,
    const float* __restrict__ bs2d, float* __restrict__ sesinf,
    float* __restrict__ h0f, u16* __restrict__ h0bf){
  int id = blockIdx.x * 4 + (threadIdx.x >> 6);
  int lane = threadIdx.x & 63;
  int n = id & 1023, b = (id >> 10) & 15, mat = id >> 14;
  const float* w = (mat ? Ws2d : Wses) + (size_t)n * 1024;
  const float* x = ctx + (size_t)b * 1024;
  float v = 0.f;
  #pragma unroll 4
  for (int k = lane; k < 1024; k += 64) v += x[k] * w[k];
  #pragma unroll
  for (int off = 32; off; off >>= 1) v += __shfl_down(v, off);
  if (lane == 0){
    if (mat == 0) sesinf[b * 1024 + n] = v;
    else {
      float t = tanhf(v + bs2d[n]);
      h0f[b * 1024 + n] = t;
      h0bf[b * 1024 + n] = f2bf(t);
    }
  }
}

// ---------------- embedding gather (bf16 rows) ----------------
__global__ void gather_kernel(const int* __restrict__ target,
                              const u16* __restrict__ embedBF, u16* __restrict__ embBF){
  int i = blockIdx.x;
  int t = target[i];
  int lane = threadIdx.x;
  *(uint4*)&embBF[(size_t)i * 512 + lane * 8] =
      *(const uint4*)&embedBF[(size_t)t * 512 + lane * 8];
}

// ---------------- bf16 GEMM: C[M][N] = A[M][K] * B[N][K]^T (+epilogue) ----------------
// SWZ: bijective XCD-aware wgid remap (requires nwg % 8 == 0)
// EPI: 0 = none -> C f32
//      3 = +add0(f32)[batch] +add1b(bf16)[row] -> pairwise-max -> bf16 outBF (N/2 cols)
//      4 = +bias(f32)[col] -> bf16 outBF
template<int EPI, int SWZ>
__global__ __launch_bounds__(256) void gemm_bt(
    const u16* __restrict__ A, const u16* __restrict__ B, float* __restrict__ C,
    int M, int N, int K,
    const float* __restrict__ bias, const float* __restrict__ add0,
    const u16* __restrict__ add1b, u16* __restrict__ outBF)
{
  __shared__ u16 sA[2][128 * 32];
  __shared__ u16 sB[2][128 * 32];
  int bx = blockIdx.x, by = blockIdx.y;
  if (SWZ){
    int nwg = gridDim.x * gridDim.y;
    int wg = by * gridDim.x + bx;
    int q = nwg >> 3;
    int nw = (wg & 7) * q + (wg >> 3);
    bx = nw % gridDim.x; by = nw / gridDim.x;
  }
  const int n0 = bx * 128;
  const int m0 = by * 128;
  const int tid = threadIdx.x;
  const int lane = tid & 63;
  const int wid = tid >> 6;
  const int wm = (wid >> 1) * 64, wn = (wid & 1) * 64;
  const int l15 = lane & 15, kg = (lane >> 4) * 8;
  (void)M;

  f32x4 zero = {0.f, 0.f, 0.f, 0.f};
  f32x4 acc[4][4];
  #pragma unroll
  for (int m = 0; m < 4; m++)
    #pragma unroll
    for (int n = 0; n < 4; n++) acc[m][n] = zero;

  auto stage = [&](int buf, int kk){
    const u16* Ab = A + (size_t)m0 * K + kk;
    const u16* Bb = B + (size_t)n0 * K + kk;
    #pragma unroll
    for (int j = 0; j < 2; j++){
      int c = j * 256 + tid;
      ASYNC16(Ab + (size_t)(c >> 2) * K + (c & 3) * 8, &sA[buf][c * 8]);
    }
    #pragma unroll
    for (int j = 0; j < 2; j++){
      int c = j * 256 + tid;
      ASYNC16(Bb + (size_t)(c >> 2) * K + (c & 3) * 8, &sB[buf][c * 8]);
    }
  };

  stage(0, 0);
  int cur = 0;
  for (int kk = 0; kk < K; kk += 32){
    __syncthreads();
    if (kk + 32 < K) stage(cur ^ 1, kk + 32);
    bf16x8 af[4], bf_[4];
    #pragma unroll
    for (int m = 0; m < 4; m++)
      af[m] = *(const bf16x8*)&sA[cur][(wm + m * 16 + l15) * 32 + kg];
    #pragma unroll
    for (int n = 0; n < 4; n++)
      bf_[n] = *(const bf16x8*)&sB[cur][(wn + n * 16 + l15) * 32 + kg];
    #pragma unroll
    for (int m = 0; m < 4; m++)
      #pragma unroll
      for (int n = 0; n < 4; n++)
        acc[m][n] = __builtin_amdgcn_mfma_f32_16x16x32_bf16(af[m], bf_[n], acc[m][n], 0, 0, 0);
    cur ^= 1;
  }

  const int rb = m0 + wm + (lane >> 4) * 4;
  const int cb = n0 + wn + l15;
  #pragma unroll
  for (int m = 0; m < 4; m++){
    #pragma unroll
    for (int n = 0; n < 4; n++){
      #pragma unroll
      for (int i = 0; i < 4; i++){
        int row = rb + m * 16 + i;
        int col = cb + n * 16;
        float v = acc[m][n][i];
        if (EPI == 4) v += bias[col];
        if (EPI == 3)
          v += add0[(row >> 8) * N + col] + b2f(add1b[(size_t)row * N + col]);
        if (EPI == 3){
          // pairwise maxout: col pairs (2e,2e+1) live in adjacent lanes
          float w = __shfl_xor(v, 1);
          if ((l15 & 1) == 0)
            outBF[(size_t)row * (N >> 1) + (col >> 1)] = f2bf(fmaxf(v, w));
        } else if (EPI == 4){
          outBF[(size_t)row * N + col] = f2bf(v);
        } else {
          C[(size_t)row * N + col] = v;
        }
      }
    }
  }
}

// ---------------- persistent GRU (R12 structure + stage rotation + bf16 xproj) ----------------
// 64 WGs x 1024 thr; WG g owns hidden cols [g*16, g*16+16); W_hh LDS-resident.
// Protocol (R4/R12, best measured): sc1 write-through publish -> vmcnt(0)
// drain -> syncthreads -> per-WG flag line -> wave0 lane-per-flag poll ->
// syncthreads; sc1 bulk re-stage. 12 MFMA waves (gate x K-quarter), gates
// threads sum 4 partials. NEW: stage chunk order rotated by g*32 so 64 WGs
// don't hammer the same L3 lines in the same order (slice de-serialization).
#define GRU_NWG 64
#define GRU_LDS 145408

__global__ __launch_bounds__(1024) void gru_kernel(
    const u16* __restrict__ WhhBF, const float* __restrict__ bhh,
    const u16* __restrict__ xprojBF, const float* __restrict__ h0f,
    const u16* __restrict__ h0bf, u16* __restrict__ hsBF, int* flags)
{
  extern __shared__ char smem[];
  u16*  Wl   = (u16*)smem;                 // [48][1032]
  u16*  hb   = Wl + 48 * 1032;             // [16][1032]
  float* gbuf = (float*)(smem + 132096);   // [12][256]  tile: [batch*16+owncol]
  float* hown = gbuf + 12 * 256;           // [16][16]

  const int g = blockIdx.x;
  const int j0 = g * 16;
  const int tid = threadIdx.x;
  const int lane = tid & 63;
  const int wid = tid >> 6;
  const int l15 = lane & 15, kh8 = (lane >> 4) * 8;

  // one-time: W_hh slice -> LDS (rows {j, H+j, 2H+j})
  for (int c = tid; c < 48 * 128; c += 1024){
    int r = c >> 7, cg = (c & 127) * 8;
    int gate = r >> 4, n = r & 15;
    *(uint4*)&Wl[r * 1032 + cg] =
        *(const uint4*)&WhhBF[(size_t)(gate * 1024 + j0 + n) * 1024 + cg];
  }
  // gates-thread setup (tid < 256): batch bb, own col jj
  const int bb = (tid & 255) >> 4, jj = tid & 15;
  float bh0 = 0.f, bh1 = 0.f, bh2 = 0.f;
  if (tid < 256){
    hown[bb * 16 + jj] = h0f[bb * 1024 + j0 + jj];
    bh0 = bhh[j0 + jj];
    bh1 = bhh[1024 + j0 + jj];
    bh2 = bhh[2048 + j0 + jj];
  }
  // rotated stage chunk indices (bijective per WG; spreads L3 slice load)
  const int cc0 = (tid + g * 32) & 2047;
  const int cc1 = (tid + 1024 + g * 32) & 2047;
  const int b0 = cc0 >> 7, cg0 = (cc0 & 127) * 8;
  const int b1 = cc1 >> 7, cg1 = (cc1 & 127) * 8;
  u32* hs32 = (u32*)hsBF;
  __syncthreads();

  for (int s = 0; s < 256; ++s){
    // ---- stage h_{s-1} into LDS (rotated order) ----
    if (s == 0){
      *(uint4*)&hb[b0 * 1032 + cg0] = *(const uint4*)&h0bf[b0 * 1024 + cg0];
      *(uint4*)&hb[b1 * 1032 + cg1] = *(const uint4*)&h0bf[b1 * 1024 + cg1];
    } else {
      u32x4 r0, r1;
      const u16* s0 = &hsBF[(size_t)((b0 << 8) + s - 1) * 1024 + cg0];
      const u16* s1 = &hsBF[(size_t)((b1 << 8) + s - 1) * 1024 + cg1];
      asm volatile("global_load_dwordx4 %0, %1, off sc1"
                   : "=v"(r0) : "v"(s0) : "memory");
      asm volatile("global_load_dwordx4 %0, %1, off sc1"
                   : "=v"(r1) : "v"(s1) : "memory");
      asm volatile("s_waitcnt vmcnt(0)" ::: "memory");
      __builtin_amdgcn_sched_barrier(0);   // rule#18 hygiene
      *(u32x4*)&hb[b0 * 1032 + cg0] = r0;
      *(u32x4*)&hb[b1 * 1032 + cg1] = r1;
    }

    // prefetch this step's x_proj scalars (gates threads only; bf16)
    float xr = 0.f, xz = 0.f, xn = 0.f;
    if (tid < 256){
      const u16* xp = xprojBF + ((size_t)(bb << 8) + s) * 3072;
      xr = b2f(xp[j0 + jj]); xz = b2f(xp[1024 + j0 + jj]); xn = b2f(xp[2048 + j0 + jj]);
    }
    __syncthreads();

    // ---- MFMA: wave wid<12 = (gate wid>>2, K-quarter wid&3) ----
    if (wid < 12){
      const int gate = wid >> 2, Koff = (wid & 3) * 256;
      f32x4 acc0 = {0.f, 0.f, 0.f, 0.f};
      f32x4 acc1 = {0.f, 0.f, 0.f, 0.f};
      const u16* wrow = &Wl[(gate * 16 + l15) * 1032 + Koff];
      const u16* hrow = &hb[l15 * 1032 + Koff];
      #pragma unroll
      for (int kk = 0; kk < 256; kk += 64){
        bf16x8 a0 = *(const bf16x8*)&hrow[kk + kh8];
        bf16x8 w0 = *(const bf16x8*)&wrow[kk + kh8];
        acc0 = __builtin_amdgcn_mfma_f32_16x16x32_bf16(a0, w0, acc0, 0, 0, 0);
        bf16x8 a1 = *(const bf16x8*)&hrow[kk + 32 + kh8];
        bf16x8 w1 = *(const bf16x8*)&wrow[kk + 32 + kh8];
        acc1 = __builtin_amdgcn_mfma_f32_16x16x32_bf16(a1, w1, acc1, 0, 0, 0);
      }
      #pragma unroll
      for (int i = 0; i < 4; ++i)
        gbuf[wid * 256 + ((lane >> 4) * 4 + i) * 16 + l15] = acc0[i] + acc1[i];
    }
    __syncthreads();

    // ---- gates (tid<256): sum 4 K-quarter partials per gate; publish ----
    if (tid < 256){
      int ic = bb * 16 + jj;
      float hr = gbuf[0 * 256 + ic] + gbuf[1 * 256 + ic] +
                 gbuf[2 * 256 + ic] + gbuf[3 * 256 + ic] + bh0;
      float hz = gbuf[4 * 256 + ic] + gbuf[5 * 256 + ic] +
                 gbuf[6 * 256 + ic] + gbuf[7 * 256 + ic] + bh1;
      float hn = gbuf[8 * 256 + ic] + gbuf[9 * 256 + ic] +
                 gbuf[10 * 256 + ic] + gbuf[11 * 256 + ic] + bh2;
      float r = 1.f / (1.f + __expf(-(xr + hr)));
      float z = 1.f / (1.f + __expf(-(xz + hz)));
      float nn = tanhf(xn + r * hn);
      float hnew = (1.f - z) * nn + z * hown[bb * 16 + jj];
      hown[bb * 16 + jj] = hnew;
      float hnext = __shfl_down(hnew, 1);
      if ((jj & 1) == 0){
        u32 pack = (u32)f2bf(hnew) | ((u32)f2bf(hnext) << 16);
        size_t e = (size_t)((bb << 8) + s) * 1024 + j0 + jj;
        __hip_atomic_store(&hs32[e >> 1], pack, __ATOMIC_RELAXED,
                           __HIP_MEMORY_SCOPE_AGENT);
      }
    }

    if (s < 255){
      asm volatile("s_waitcnt vmcnt(0)" ::: "memory");
      __syncthreads();
      if (tid == 0)
        __hip_atomic_store(&flags[g * 32], s + 1, __ATOMIC_RELAXED,
                           __HIP_MEMORY_SCOPE_AGENT);
      if (wid == 0){
        while (__hip_atomic_load(&flags[lane * 32], __ATOMIC_RELAXED,
                                 __HIP_MEMORY_SCOPE_AGENT) <= s)
          __builtin_amdgcn_s_sleep(1);
      }
      __syncthreads();
    }
  }
}

extern "C" void kernel_launch(void* const* d_in, const int* in_sizes, int n_in,
                              void* d_out, int out_size, void* d_ws, size_t ws_size,
                              hipStream_t stream)
{
  const float* ctx    = (const float*)d_in[0];
  const int*   target = (const int*)d_in[1];
  const float* embed  = (const float*)d_in[2];
  const float* Ws2d   = (const float*)d_in[3];
  const float* bs2d   = (const float*)d_in[4];
  const float* Wdec   = (const float*)d_in[5];
  const float* Wses   = (const float*)d_in[6];
  const float* Wemb   = (const float*)d_in[7];
  const float* bemb   = (const float*)d_in[8];
  const float* Wih    = (const float*)d_in[9];
  const float* Whh    = (const float*)d_in[10];
  const float* bih    = (const float*)d_in[11];
  const float* bhh    = (const float*)d_in[12];
  float* out = (float*)d_out;

  char* ws = (char*)d_ws;
  size_t off = 0;
  auto alloc = [&](size_t bytes)->char*{
    char* p = ws + off; off += (bytes + 255) & ~(size_t)255; return p;
  };
  u16*   embedBF  = (u16*)alloc(32000ull * 512 * 2);
  u16*   WihBF    = (u16*)alloc(3072ull * 512 * 2);
  u16*   WembBF   = (u16*)alloc(1024ull * 512 * 2);
  u16*   WdecBF   = (u16*)alloc(1024ull * 1024 * 2);
  u16*   WhhBF    = (u16*)alloc(3072ull * 1024 * 2);
  u16*   embBF    = (u16*)alloc(4096ull * 512 * 2);
  u16*   xprojBF  = (u16*)alloc(4096ull * 3072 * 2);
  u16*   embinfBF = (u16*)alloc(4096ull * 1024 * 2);
  float* sesinf   = (float*)alloc(16ull * 1024 * 4);
  float* h0f      = (float*)alloc(16ull * 1024 * 4);
  u16*   h0bf     = (u16*)alloc(16ull * 1024 * 2);
  u16*   hsBF     = (u16*)alloc(4096ull * 1024 * 2);
  u16*   mxBF     = (u16*)alloc(4096ull * 512 * 2);
  int*   flags    = (int*)alloc(16384);
  (void)ws_size; (void)in_sizes; (void)n_in; (void)out_size;

  hipFuncSetAttribute((const void*)gru_kernel,
                      hipFuncAttributeMaxDynamicSharedMemorySize, GRU_LDS);
  hipMemsetAsync(flags, 0, 16384, stream);

  // fused conversion of all 5 weight tensors (22675456 elems / 2048 per block)
  conv_all_kernel<<<11072, 256, 0, stream>>>(embed, Wih, Wemb, Wdec, Whh,
                                             embedBF, WihBF, WembBF, WdecBF, WhhBF);

  ctx_kernel<<<8192, 256, 0, stream>>>(ctx, Wses, Ws2d, bs2d, sesinf, h0f, h0bf);
  gather_kernel<<<4096, 64, 0, stream>>>(target, embedBF, embBF);

  // x_proj = emb @ W_ih^T + b_ih (bf16 out); emb_inf = emb @ W_emb^T + b_emb (bf16 out)
  gemm_bt<4,0><<<dim3(3072 / 128, 4096 / 128), 256, 0, stream>>>(
      embBF, WihBF, nullptr, 4096, 3072, 512, bih, nullptr, nullptr, xprojBF);
  gemm_bt<4,0><<<dim3(1024 / 128, 4096 / 128), 256, 0, stream>>>(
      embBF, WembBF, nullptr, 4096, 1024, 512, bemb, nullptr, nullptr, embinfBF);

  gru_kernel<<<GRU_NWG, 1024, GRU_LDS, stream>>>(WhhBF, bhh, xprojBF, h0f, h0bf,
                                                 hsBF, flags);

  // total = hs @ W_dec^T + ses_inf[b] + emb_inf ; fused pairwise-maxout -> mxBF
  gemm_bt<3,0><<<dim3(1024 / 128, 4096 / 128), 256, 0, stream>>>(
      hsBF, WdecBF, nullptr, 4096, 1024, 1024, nullptr, sesinf, embinfBF, mxBF);

  // logits = mx @ embed^T  (XCD-swizzled: 8000 WGs % 8 == 0)
  gemm_bt<0,1><<<dim3(32000 / 128, 4096 / 128), 256, 0, stream>>>(
      mxBF, embedBF, out, 4096, 32000, 512, nullptr, nullptr, nullptr, nullptr);
}

// Round 15
// 1154.032 us; speedup vs baseline: 1.2032x; 1.0406x over previous
//
#include <hip/hip_runtime.h>

typedef unsigned short u16;
typedef unsigned int u32;
typedef __attribute__((ext_vector_type(8))) __bf16 bf16x8;
typedef __attribute__((ext_vector_type(4))) float f32x4;
typedef __attribute__((ext_vector_type(4))) u32 u32x4;

#define ASYNC16(g, l) __builtin_amdgcn_global_load_lds( \
    (const __attribute__((address_space(1))) unsigned int*)(g), \
    (__attribute__((address_space(3))) unsigned int*)(l), 16, 0, 0)

__device__ __forceinline__ u16 f2bf(float f){
  unsigned u = __float_as_uint(f);
  unsigned r = u + 0x7fffu + ((u >> 16) & 1u);
  return (u16)(r >> 16);
}

// ---------------- fused fp32 -> bf16 conversion (all 5 weight tensors) ----------------
// segment cumulative sizes (elements), all 8-divisible:
// embed 16384000 | Wih 1572864 | Wemb 524288 | Wdec 1048576 | Whh 3145728
__global__ __launch_bounds__(256) void conv_all_kernel(
    const float* __restrict__ e, const float* __restrict__ wih,
    const float* __restrict__ wemb, const float* __restrict__ wdec,
    const float* __restrict__ whh,
    u16* __restrict__ oe, u16* __restrict__ oih, u16* __restrict__ oemb,
    u16* __restrict__ odec, u16* __restrict__ ohh)
{
  long i = ((long)blockIdx.x * 256 + threadIdx.x) * 8;   // < 22675456
  const float* src; u16* dst; long off;
  if (i < 16384000L)      { src = e;    dst = oe;   off = i; }
  else if (i < 17956864L) { src = wih;  dst = oih;  off = i - 16384000L; }
  else if (i < 18481152L) { src = wemb; dst = oemb; off = i - 17956864L; }
  else if (i < 19529728L) { src = wdec; dst = odec; off = i - 18481152L; }
  else                    { src = whh;  dst = ohh;  off = i - 19529728L; }
  float4 a = *(const float4*)&src[off];
  float4 b = *(const float4*)&src[off + 4];
  u16 r[8] = {f2bf(a.x), f2bf(a.y), f2bf(a.z), f2bf(a.w),
              f2bf(b.x), f2bf(b.y), f2bf(b.z), f2bf(b.w)};
  *(uint4*)&dst[off] = *(const uint4*)r;
}

// ---------------- ctx projections: ses_inf, h0 ----------------
__global__ __launch_bounds__(256) void ctx_kernel(const float* __restrict__ ctx,
    const float* __restrict__ Wses, const float* __restrict__ Ws2d,
    const float* __restrict__ bs2d, float* __restrict__ sesinf,
    float* __restrict__ h0f, u16* __restrict__ h0bf){
  int id = blockIdx.x * 4 + (threadIdx.x >> 6);
  int lane = threadIdx.x & 63;
  int n = id & 1023, b = (id >> 10) & 15, mat = id >> 14;
  const float* w = (mat ? Ws2d : Wses) + (size_t)n * 1024;
  const float* x = ctx + (size_t)b * 1024;
  float v = 0.f;
  #pragma unroll 4
  for (int k = lane; k < 1024; k += 64) v += x[k] * w[k];
  #pragma unroll
  for (int off = 32; off; off >>= 1) v += __shfl_down(v, off);
  if (lane == 0){
    if (mat == 0) sesinf[b * 1024 + n] = v;
    else {
      float t = tanhf(v + bs2d[n]);
      h0f[b * 1024 + n] = t;
      h0bf[b * 1024 + n] = f2bf(t);
    }
  }
}

// ---------------- embedding gather (bf16 rows) ----------------
__global__ void gather_kernel(const int* __restrict__ target,
                              const u16* __restrict__ embedBF, u16* __restrict__ embBF){
  int i = blockIdx.x;
  int t = target[i];
  int lane = threadIdx.x;
  *(uint4*)&embBF[(size_t)i * 512 + lane * 8] =
      *(const uint4*)&embedBF[(size_t)t * 512 + lane * 8];
}

// ---------------- bf16 GEMM: C[M][N] = A[M][K] * B[N][K]^T (+epilogue) ----------------
// SWZ: bijective XCD-aware wgid remap (requires nwg % 8 == 0)
// EPI: 0=none, 1=+bias[col], 3=+add0+add1 -> pairwise-max -> bf16 mxout
template<int EPI, int SWZ>
__global__ __launch_bounds__(256) void gemm_bt(
    const u16* __restrict__ A, const u16* __restrict__ B, float* __restrict__ C,
    int M, int N, int K,
    const float* __restrict__ bias, const float* __restrict__ add0,
    const float* __restrict__ add1, u16* __restrict__ mxout)
{
  __shared__ u16 sA[2][128 * 32];
  __shared__ u16 sB[2][128 * 32];
  int bx = blockIdx.x, by = blockIdx.y;
  if (SWZ){
    int nwg = gridDim.x * gridDim.y;
    int wg = by * gridDim.x + bx;
    int q = nwg >> 3;
    int nw = (wg & 7) * q + (wg >> 3);
    bx = nw % gridDim.x; by = nw / gridDim.x;
  }
  const int n0 = bx * 128;
  const int m0 = by * 128;
  const int tid = threadIdx.x;
  const int lane = tid & 63;
  const int wid = tid >> 6;
  const int wm = (wid >> 1) * 64, wn = (wid & 1) * 64;
  const int l15 = lane & 15, kg = (lane >> 4) * 8;
  (void)M;

  f32x4 zero = {0.f, 0.f, 0.f, 0.f};
  f32x4 acc[4][4];
  #pragma unroll
  for (int m = 0; m < 4; m++)
    #pragma unroll
    for (int n = 0; n < 4; n++) acc[m][n] = zero;

  auto stage = [&](int buf, int kk){
    const u16* Ab = A + (size_t)m0 * K + kk;
    const u16* Bb = B + (size_t)n0 * K + kk;
    #pragma unroll
    for (int j = 0; j < 2; j++){
      int c = j * 256 + tid;
      ASYNC16(Ab + (size_t)(c >> 2) * K + (c & 3) * 8, &sA[buf][c * 8]);
    }
    #pragma unroll
    for (int j = 0; j < 2; j++){
      int c = j * 256 + tid;
      ASYNC16(Bb + (size_t)(c >> 2) * K + (c & 3) * 8, &sB[buf][c * 8]);
    }
  };

  stage(0, 0);
  int cur = 0;
  for (int kk = 0; kk < K; kk += 32){
    __syncthreads();
    if (kk + 32 < K) stage(cur ^ 1, kk + 32);
    bf16x8 af[4], bf_[4];
    #pragma unroll
    for (int m = 0; m < 4; m++)
      af[m] = *(const bf16x8*)&sA[cur][(wm + m * 16 + l15) * 32 + kg];
    #pragma unroll
    for (int n = 0; n < 4; n++)
      bf_[n] = *(const bf16x8*)&sB[cur][(wn + n * 16 + l15) * 32 + kg];
    #pragma unroll
    for (int m = 0; m < 4; m++)
      #pragma unroll
      for (int n = 0; n < 4; n++)
        acc[m][n] = __builtin_amdgcn_mfma_f32_16x16x32_bf16(af[m], bf_[n], acc[m][n], 0, 0, 0);
    cur ^= 1;
  }

  const int rb = m0 + wm + (lane >> 4) * 4;
  const int cb = n0 + wn + l15;
  #pragma unroll
  for (int m = 0; m < 4; m++){
    #pragma unroll
    for (int n = 0; n < 4; n++){
      #pragma unroll
      for (int i = 0; i < 4; i++){
        int row = rb + m * 16 + i;
        int col = cb + n * 16;
        float v = acc[m][n][i];
        if (EPI == 1) v += bias[col];
        if (EPI == 3)
          v += add0[(row >> 8) * N + col] + add1[(size_t)row * N + col];
        if (EPI == 3){
          // pairwise maxout: col pairs (2e,2e+1) live in adjacent lanes
          float w = __shfl_xor(v, 1);
          if ((l15 & 1) == 0)
            mxout[(size_t)row * (N >> 1) + (col >> 1)] = f2bf(fmaxf(v, w));
        } else {
          C[(size_t)row * N + col] = v;
        }
      }
    }
  }
}

// ---------------- persistent GRU (R12 exact — best measured: 806 us) ----------------
// 64 WGs x 1024 thr; WG g owns hidden cols [g*16, g*16+16); W_hh LDS-resident.
// Protocol: sc1 write-through publish -> vmcnt(0) drain -> syncthreads ->
// per-WG flag line -> wave0 lane-per-flag poll -> syncthreads; sc1 bulk
// re-stage. 12 MFMA waves (gate x K-quarter), gates threads sum 4 partials.
// Do NOT perturb: rotation (R14 -39us), W-streaming (R11 -2.5ms), tags
// (R5/R6/R9/R13 all lost), flag-only gating (R7/R8 raced).
#define GRU_NWG 64
#define GRU_LDS 145408

__global__ __launch_bounds__(1024) void gru_kernel(
    const u16* __restrict__ WhhBF, const float* __restrict__ bhh,
    const float* __restrict__ xproj, const float* __restrict__ h0f,
    const u16* __restrict__ h0bf, u16* __restrict__ hsBF, int* flags)
{
  extern __shared__ char smem[];
  u16*  Wl   = (u16*)smem;                 // [48][1032]
  u16*  hb   = Wl + 48 * 1032;             // [16][1032]
  float* gbuf = (float*)(smem + 132096);   // [12][256]  tile: [batch*16+owncol]
  float* hown = gbuf + 12 * 256;           // [16][16]

  const int g = blockIdx.x;
  const int j0 = g * 16;
  const int tid = threadIdx.x;
  const int lane = tid & 63;
  const int wid = tid >> 6;
  const int l15 = lane & 15, kh8 = (lane >> 4) * 8;

  // one-time: W_hh slice -> LDS (rows {j, H+j, 2H+j})
  for (int c = tid; c < 48 * 128; c += 1024){
    int r = c >> 7, cg = (c & 127) * 8;
    int gate = r >> 4, n = r & 15;
    *(uint4*)&Wl[r * 1032 + cg] =
        *(const uint4*)&WhhBF[(size_t)(gate * 1024 + j0 + n) * 1024 + cg];
  }
  // gates-thread setup (tid < 256): batch bb, own col jj
  const int bb = (tid & 255) >> 4, jj = tid & 15;
  float bh0 = 0.f, bh1 = 0.f, bh2 = 0.f;
  if (tid < 256){
    hown[bb * 16 + jj] = h0f[bb * 1024 + j0 + jj];
    bh0 = bhh[j0 + jj];
    bh1 = bhh[1024 + j0 + jj];
    bh2 = bhh[2048 + j0 + jj];
  }
  // stage addressing for this thread's two 8-col chunks
  const int c0 = tid,         b0 = c0 >> 7, cg0 = (c0 & 127) * 8;
  const int c1 = tid + 1024,  b1 = c1 >> 7, cg1 = (c1 & 127) * 8;
  u32* hs32 = (u32*)hsBF;
  __syncthreads();

  for (int s = 0; s < 256; ++s){
    // ---- stage h_{s-1} into LDS: 1024 thr x 2 dwordx4 ----
    if (s == 0){
      *(uint4*)&hb[b0 * 1032 + cg0] = *(const uint4*)&h0bf[b0 * 1024 + cg0];
      *(uint4*)&hb[b1 * 1032 + cg1] = *(const uint4*)&h0bf[b1 * 1024 + cg1];
    } else {
      u32x4 r0, r1;
      const u16* s0 = &hsBF[(size_t)((b0 << 8) + s - 1) * 1024 + cg0];
      const u16* s1 = &hsBF[(size_t)((b1 << 8) + s - 1) * 1024 + cg1];
      asm volatile("global_load_dwordx4 %0, %1, off sc1"
                   : "=v"(r0) : "v"(s0) : "memory");
      asm volatile("global_load_dwordx4 %0, %1, off sc1"
                   : "=v"(r1) : "v"(s1) : "memory");
      asm volatile("s_waitcnt vmcnt(0)" ::: "memory");
      __builtin_amdgcn_sched_barrier(0);   // rule#18 hygiene
      *(u32x4*)&hb[b0 * 1032 + cg0] = r0;
      *(u32x4*)&hb[b1 * 1032 + cg1] = r1;
    }

    // prefetch this step's x_proj scalars (gates threads only)
    float xr = 0.f, xz = 0.f, xn = 0.f;
    if (tid < 256){
      const float* xp = xproj + ((size_t)(bb << 8) + s) * 3072;
      xr = xp[j0 + jj]; xz = xp[1024 + j0 + jj]; xn = xp[2048 + j0 + jj];
    }
    __syncthreads();

    // ---- MFMA: wave wid<12 = (gate wid>>2, K-quarter wid&3) ----
    if (wid < 12){
      const int gate = wid >> 2, Koff = (wid & 3) * 256;
      f32x4 acc0 = {0.f, 0.f, 0.f, 0.f};
      f32x4 acc1 = {0.f, 0.f, 0.f, 0.f};
      const u16* wrow = &Wl[(gate * 16 + l15) * 1032 + Koff];
      const u16* hrow = &hb[l15 * 1032 + Koff];
      #pragma unroll
      for (int kk = 0; kk < 256; kk += 64){
        bf16x8 a0 = *(const bf16x8*)&hrow[kk + kh8];
        bf16x8 w0 = *(const bf16x8*)&wrow[kk + kh8];
        acc0 = __builtin_amdgcn_mfma_f32_16x16x32_bf16(a0, w0, acc0, 0, 0, 0);
        bf16x8 a1 = *(const bf16x8*)&hrow[kk + 32 + kh8];
        bf16x8 w1 = *(const bf16x8*)&wrow[kk + 32 + kh8];
        acc1 = __builtin_amdgcn_mfma_f32_16x16x32_bf16(a1, w1, acc1, 0, 0, 0);
      }
      #pragma unroll
      for (int i = 0; i < 4; ++i)
        gbuf[wid * 256 + ((lane >> 4) * 4 + i) * 16 + l15] = acc0[i] + acc1[i];
    }
    __syncthreads();

    // ---- gates (tid<256): sum 4 K-quarter partials per gate; publish ----
    if (tid < 256){
      int ic = bb * 16 + jj;
      float hr = gbuf[0 * 256 + ic] + gbuf[1 * 256 + ic] +
                 gbuf[2 * 256 + ic] + gbuf[3 * 256 + ic] + bh0;
      float hz = gbuf[4 * 256 + ic] + gbuf[5 * 256 + ic] +
                 gbuf[6 * 256 + ic] + gbuf[7 * 256 + ic] + bh1;
      float hn = gbuf[8 * 256 + ic] + gbuf[9 * 256 + ic] +
                 gbuf[10 * 256 + ic] + gbuf[11 * 256 + ic] + bh2;
      float r = 1.f / (1.f + __expf(-(xr + hr)));
      float z = 1.f / (1.f + __expf(-(xz + hz)));
      float nn = tanhf(xn + r * hn);
      float hnew = (1.f - z) * nn + z * hown[bb * 16 + jj];
      hown[bb * 16 + jj] = hnew;
      float hnext = __shfl_down(hnew, 1);
      if ((jj & 1) == 0){
        u32 pack = (u32)f2bf(hnew) | ((u32)f2bf(hnext) << 16);
        size_t e = (size_t)((bb << 8) + s) * 1024 + j0 + jj;
        __hip_atomic_store(&hs32[e >> 1], pack, __ATOMIC_RELAXED,
                           __HIP_MEMORY_SCOPE_AGENT);
      }
    }

    if (s < 255){
      asm volatile("s_waitcnt vmcnt(0)" ::: "memory");
      __syncthreads();
      if (tid == 0)
        __hip_atomic_store(&flags[g * 32], s + 1, __ATOMIC_RELAXED,
                           __HIP_MEMORY_SCOPE_AGENT);
      if (wid == 0){
        while (__hip_atomic_load(&flags[lane * 32], __ATOMIC_RELAXED,
                                 __HIP_MEMORY_SCOPE_AGENT) <= s)
          __builtin_amdgcn_s_sleep(1);
      }
      __syncthreads();
    }
  }
}

extern "C" void kernel_launch(void* const* d_in, const int* in_sizes, int n_in,
                              void* d_out, int out_size, void* d_ws, size_t ws_size,
                              hipStream_t stream)
{
  const float* ctx    = (const float*)d_in[0];
  const int*   target = (const int*)d_in[1];
  const float* embed  = (const float*)d_in[2];
  const float* Ws2d   = (const float*)d_in[3];
  const float* bs2d   = (const float*)d_in[4];
  const float* Wdec   = (const float*)d_in[5];
  const float* Wses   = (const float*)d_in[6];
  const float* Wemb   = (const float*)d_in[7];
  const float* bemb   = (const float*)d_in[8];
  const float* Wih    = (const float*)d_in[9];
  const float* Whh    = (const float*)d_in[10];
  const float* bih    = (const float*)d_in[11];
  const float* bhh    = (const float*)d_in[12];
  float* out = (float*)d_out;

  char* ws = (char*)d_ws;
  size_t off = 0;
  auto alloc = [&](size_t bytes)->char*{
    char* p = ws + off; off += (bytes + 255) & ~(size_t)255; return p;
  };
  u16*   embedBF = (u16*)alloc(32000ull * 512 * 2);
  u16*   WihBF   = (u16*)alloc(3072ull * 512 * 2);
  u16*   WembBF  = (u16*)alloc(1024ull * 512 * 2);
  u16*   WdecBF  = (u16*)alloc(1024ull * 1024 * 2);
  u16*   WhhBF   = (u16*)alloc(3072ull * 1024 * 2);
  u16*   embBF   = (u16*)alloc(4096ull * 512 * 2);
  float* xproj   = (float*)alloc(4096ull * 3072 * 4);
  float* embinf  = (float*)alloc(4096ull * 1024 * 4);
  float* sesinf  = (float*)alloc(16ull * 1024 * 4);
  float* h0f     = (float*)alloc(16ull * 1024 * 4);
  u16*   h0bf    = (u16*)alloc(16ull * 1024 * 2);
  u16*   hsBF    = (u16*)alloc(4096ull * 1024 * 2);
  u16*   mxBF    = (u16*)alloc(4096ull * 512 * 2);
  int*   flags   = (int*)alloc(16384);
  (void)ws_size; (void)in_sizes; (void)n_in; (void)out_size;

  hipFuncSetAttribute((const void*)gru_kernel,
                      hipFuncAttributeMaxDynamicSharedMemorySize, GRU_LDS);
  hipMemsetAsync(flags, 0, 16384, stream);

  // fused conversion of all 5 weight tensors (22675456 elems / 2048 per block)
  conv_all_kernel<<<11072, 256, 0, stream>>>(embed, Wih, Wemb, Wdec, Whh,
                                             embedBF, WihBF, WembBF, WdecBF, WhhBF);

  ctx_kernel<<<8192, 256, 0, stream>>>(ctx, Wses, Ws2d, bs2d, sesinf, h0f, h0bf);
  gather_kernel<<<4096, 64, 0, stream>>>(target, embedBF, embBF);

  // x_proj = emb @ W_ih^T + b_ih ; emb_inf = emb @ W_emb^T + b_emb
  gemm_bt<1,0><<<dim3(3072 / 128, 4096 / 128), 256, 0, stream>>>(
      embBF, WihBF, xproj, 4096, 3072, 512, bih, nullptr, nullptr, nullptr);
  gemm_bt<1,0><<<dim3(1024 / 128, 4096 / 128), 256, 0, stream>>>(
      embBF, WembBF, embinf, 4096, 1024, 512, bemb, nullptr, nullptr, nullptr);

  gru_kernel<<<GRU_NWG, 1024, GRU_LDS, stream>>>(WhhBF, bhh, xproj, h0f, h0bf,
                                                 hsBF, flags);

  // total = hs @ W_dec^T + ses_inf[b] + emb_inf ; fused pairwise-maxout -> mxBF
  gemm_bt<3,0><<<dim3(1024 / 128, 4096 / 128), 256, 0, stream>>>(
      hsBF, WdecBF, nullptr, 4096, 1024, 1024, nullptr, sesinf, embinf, mxBF);

  // logits = mx @ embed^T  (XCD-swizzled: 8000 WGs % 8 == 0)
  gemm_bt<0,1><<<dim3(32000 / 128, 4096 / 128), 256, 0, stream>>>(
      mxBF, embedBF, out, 4096, 32000, 512, nullptr, nullptr, nullptr, nullptr);
}

// Round 16
// 1151.758 us; speedup vs baseline: 1.2056x; 1.0020x over previous
//
#include <hip/hip_runtime.h>

typedef unsigned short u16;
typedef unsigned int u32;
typedef __attribute__((ext_vector_type(8))) __bf16 bf16x8;
typedef __attribute__((ext_vector_type(4))) float f32x4;
typedef __attribute__((ext_vector_type(4))) u32 u32x4;

#define ASYNC16(g, l) __builtin_amdgcn_global_load_lds( \
    (const __attribute__((address_space(1))) unsigned int*)(g), \
    (__attribute__((address_space(3))) unsigned int*)(l), 16, 0, 0)

__device__ __forceinline__ u16 f2bf(float f){
  unsigned u = __float_as_uint(f);
  unsigned r = u + 0x7fffu + ((u >> 16) & 1u);
  return (u16)(r >> 16);
}

// ---------------- fused: fp32->bf16 conversion (5 weights) + ctx projections ----------------
// conv blocks [0, 11072): segment cumulative sizes (elements), all 8-divisible:
// embed 16384000 | Wih 1572864 | Wemb 524288 | Wdec 1048576 | Whh 3145728
// ctx blocks [11072, 19264): ses_inf = ctx@Wses^T ; h0 = tanh(ctx@Ws2d^T + b)
__global__ __launch_bounds__(256) void fused_pre_kernel(
    const float* __restrict__ e, const float* __restrict__ wih,
    const float* __restrict__ wemb, const float* __restrict__ wdec,
    const float* __restrict__ whh,
    u16* __restrict__ oe, u16* __restrict__ oih, u16* __restrict__ oemb,
    u16* __restrict__ odec, u16* __restrict__ ohh,
    const float* __restrict__ ctx, const float* __restrict__ Wses,
    const float* __restrict__ Ws2d, const float* __restrict__ bs2d,
    float* __restrict__ sesinf, float* __restrict__ h0f, u16* __restrict__ h0bf)
{
  if (blockIdx.x < 11072){
    long i = ((long)blockIdx.x * 256 + threadIdx.x) * 8;   // < 22675456
    const float* src; u16* dst; long off;
    if (i < 16384000L)      { src = e;    dst = oe;   off = i; }
    else if (i < 17956864L) { src = wih;  dst = oih;  off = i - 16384000L; }
    else if (i < 18481152L) { src = wemb; dst = oemb; off = i - 17956864L; }
    else if (i < 19529728L) { src = wdec; dst = odec; off = i - 18481152L; }
    else                    { src = whh;  dst = ohh;  off = i - 19529728L; }
    float4 a = *(const float4*)&src[off];
    float4 b = *(const float4*)&src[off + 4];
    u16 r[8] = {f2bf(a.x), f2bf(a.y), f2bf(a.z), f2bf(a.w),
                f2bf(b.x), f2bf(b.y), f2bf(b.z), f2bf(b.w)};
    *(uint4*)&dst[off] = *(const uint4*)r;
  } else {
    int id = (blockIdx.x - 11072) * 4 + (threadIdx.x >> 6);
    int lane = threadIdx.x & 63;
    int n = id & 1023, b = (id >> 10) & 15, mat = id >> 14;
    const float* w = (mat ? Ws2d : Wses) + (size_t)n * 1024;
    const float* x = ctx + (size_t)b * 1024;
    float v = 0.f;
    #pragma unroll 4
    for (int k = lane; k < 1024; k += 64) v += x[k] * w[k];
    #pragma unroll
    for (int off = 32; off; off >>= 1) v += __shfl_down(v, off);
    if (lane == 0){
      if (mat == 0) sesinf[b * 1024 + n] = v;
      else {
        float t = tanhf(v + bs2d[n]);
        h0f[b * 1024 + n] = t;
        h0bf[b * 1024 + n] = f2bf(t);
      }
    }
  }
}

// ---------------- embedding gather (bf16 rows) ----------------
__global__ void gather_kernel(const int* __restrict__ target,
                              const u16* __restrict__ embedBF, u16* __restrict__ embBF){
  int i = blockIdx.x;
  int t = target[i];
  int lane = threadIdx.x;
  *(uint4*)&embBF[(size_t)i * 512 + lane * 8] =
      *(const uint4*)&embedBF[(size_t)t * 512 + lane * 8];
}

// ---------------- bf16 GEMM: C[M][N] = A[M][K] * B[N][K]^T (+epilogue) ----------------
// SWZ: bijective XCD-aware wgid remap (requires nwg % 8 == 0)
// EPI: 0 = none -> C f32
//      3 = +add0[f32, batch stride N] +add1[f32, row stride a1s] -> pairwise-max -> bf16 mxout
//      5 = +dual bias (col<3072 ? bias[col] : bias2[col-3072]) -> C f32
template<int EPI, int SWZ>
__global__ __launch_bounds__(256) void gemm_bt(
    const u16* __restrict__ A, const u16* __restrict__ B, float* __restrict__ C,
    int M, int N, int K,
    const float* __restrict__ bias, const float* __restrict__ bias2,
    const float* __restrict__ add0, const float* __restrict__ add1, int a1s,
    u16* __restrict__ mxout)
{
  __shared__ u16 sA[2][128 * 32];
  __shared__ u16 sB[2][128 * 32];
  int bx = blockIdx.x, by = blockIdx.y;
  if (SWZ){
    int nwg = gridDim.x * gridDim.y;
    int wg = by * gridDim.x + bx;
    int q = nwg >> 3;
    int nw = (wg & 7) * q + (wg >> 3);
    bx = nw % gridDim.x; by = nw / gridDim.x;
  }
  const int n0 = bx * 128;
  const int m0 = by * 128;
  const int tid = threadIdx.x;
  const int lane = tid & 63;
  const int wid = tid >> 6;
  const int wm = (wid >> 1) * 64, wn = (wid & 1) * 64;
  const int l15 = lane & 15, kg = (lane >> 4) * 8;
  (void)M;

  f32x4 zero = {0.f, 0.f, 0.f, 0.f};
  f32x4 acc[4][4];
  #pragma unroll
  for (int m = 0; m < 4; m++)
    #pragma unroll
    for (int n = 0; n < 4; n++) acc[m][n] = zero;

  auto stage = [&](int buf, int kk){
    const u16* Ab = A + (size_t)m0 * K + kk;
    const u16* Bb = B + (size_t)n0 * K + kk;
    #pragma unroll
    for (int j = 0; j < 2; j++){
      int c = j * 256 + tid;
      ASYNC16(Ab + (size_t)(c >> 2) * K + (c & 3) * 8, &sA[buf][c * 8]);
    }
    #pragma unroll
    for (int j = 0; j < 2; j++){
      int c = j * 256 + tid;
      ASYNC16(Bb + (size_t)(c >> 2) * K + (c & 3) * 8, &sB[buf][c * 8]);
    }
  };

  stage(0, 0);
  int cur = 0;
  for (int kk = 0; kk < K; kk += 32){
    __syncthreads();
    if (kk + 32 < K) stage(cur ^ 1, kk + 32);
    bf16x8 af[4], bf_[4];
    #pragma unroll
    for (int m = 0; m < 4; m++)
      af[m] = *(const bf16x8*)&sA[cur][(wm + m * 16 + l15) * 32 + kg];
    #pragma unroll
    for (int n = 0; n < 4; n++)
      bf_[n] = *(const bf16x8*)&sB[cur][(wn + n * 16 + l15) * 32 + kg];
    #pragma unroll
    for (int m = 0; m < 4; m++)
      #pragma unroll
      for (int n = 0; n < 4; n++)
        acc[m][n] = __builtin_amdgcn_mfma_f32_16x16x32_bf16(af[m], bf_[n], acc[m][n], 0, 0, 0);
    cur ^= 1;
  }

  const int rb = m0 + wm + (lane >> 4) * 4;
  const int cb = n0 + wn + l15;
  #pragma unroll
  for (int m = 0; m < 4; m++){
    #pragma unroll
    for (int n = 0; n < 4; n++){
      #pragma unroll
      for (int i = 0; i < 4; i++){
        int row = rb + m * 16 + i;
        int col = cb + n * 16;
        float v = acc[m][n][i];
        if (EPI == 5) v += (col < 3072) ? bias[col] : bias2[col - 3072];
        if (EPI == 3)
          v += add0[(row >> 8) * N + col] + add1[(size_t)row * a1s + col];
        if (EPI == 3){
          // pairwise maxout: col pairs (2e,2e+1) live in adjacent lanes
          float w = __shfl_xor(v, 1);
          if ((l15 & 1) == 0)
            mxout[(size_t)row * (N >> 1) + (col >> 1)] = f2bf(fmaxf(v, w));
        } else {
          C[(size_t)row * N + col] = v;
        }
      }
    }
  }
}

// ---------------- persistent GRU (R12 exact — best measured: 791 us) ----------------
// 64 WGs x 1024 thr; WG g owns hidden cols [g*16, g*16+16); W_hh LDS-resident.
// Protocol: sc1 write-through publish -> vmcnt(0) drain -> syncthreads ->
// per-WG flag line -> wave0 lane-per-flag poll -> syncthreads; sc1 bulk
// re-stage. 12 MFMA waves (gate x K-quarter), gates threads sum 4 partials.
// Do NOT perturb: rotation (R14 -39us), W-streaming (R11 -2.5ms), tags
// (R5/R6/R9/R13 all lost), flag-only gating (R7/R8 raced).
// ONLY change vs R15: xproj row stride 3072 -> 4096 (combined comb buffer).
#define GRU_NWG 64
#define GRU_LDS 145408

__global__ __launch_bounds__(1024) void gru_kernel(
    const u16* __restrict__ WhhBF, const float* __restrict__ bhh,
    const float* __restrict__ xproj, const float* __restrict__ h0f,
    const u16* __restrict__ h0bf, u16* __restrict__ hsBF, int* flags)
{
  extern __shared__ char smem[];
  u16*  Wl   = (u16*)smem;                 // [48][1032]
  u16*  hb   = Wl + 48 * 1032;             // [16][1032]
  float* gbuf = (float*)(smem + 132096);   // [12][256]  tile: [batch*16+owncol]
  float* hown = gbuf + 12 * 256;           // [16][16]

  const int g = blockIdx.x;
  const int j0 = g * 16;
  const int tid = threadIdx.x;
  const int lane = tid & 63;
  const int wid = tid >> 6;
  const int l15 = lane & 15, kh8 = (lane >> 4) * 8;

  // one-time: W_hh slice -> LDS (rows {j, H+j, 2H+j})
  for (int c = tid; c < 48 * 128; c += 1024){
    int r = c >> 7, cg = (c & 127) * 8;
    int gate = r >> 4, n = r & 15;
    *(uint4*)&Wl[r * 1032 + cg] =
        *(const uint4*)&WhhBF[(size_t)(gate * 1024 + j0 + n) * 1024 + cg];
  }
  // gates-thread setup (tid < 256): batch bb, own col jj
  const int bb = (tid & 255) >> 4, jj = tid & 15;
  float bh0 = 0.f, bh1 = 0.f, bh2 = 0.f;
  if (tid < 256){
    hown[bb * 16 + jj] = h0f[bb * 1024 + j0 + jj];
    bh0 = bhh[j0 + jj];
    bh1 = bhh[1024 + j0 + jj];
    bh2 = bhh[2048 + j0 + jj];
  }
  // stage addressing for this thread's two 8-col chunks
  const int c0 = tid,         b0 = c0 >> 7, cg0 = (c0 & 127) * 8;
  const int c1 = tid + 1024,  b1 = c1 >> 7, cg1 = (c1 & 127) * 8;
  u32* hs32 = (u32*)hsBF;
  __syncthreads();

  for (int s = 0; s < 256; ++s){
    // ---- stage h_{s-1} into LDS: 1024 thr x 2 dwordx4 ----
    if (s == 0){
      *(uint4*)&hb[b0 * 1032 + cg0] = *(const uint4*)&h0bf[b0 * 1024 + cg0];
      *(uint4*)&hb[b1 * 1032 + cg1] = *(const uint4*)&h0bf[b1 * 1024 + cg1];
    } else {
      u32x4 r0, r1;
      const u16* s0 = &hsBF[(size_t)((b0 << 8) + s - 1) * 1024 + cg0];
      const u16* s1 = &hsBF[(size_t)((b1 << 8) + s - 1) * 1024 + cg1];
      asm volatile("global_load_dwordx4 %0, %1, off sc1"
                   : "=v"(r0) : "v"(s0) : "memory");
      asm volatile("global_load_dwordx4 %0, %1, off sc1"
                   : "=v"(r1) : "v"(s1) : "memory");
      asm volatile("s_waitcnt vmcnt(0)" ::: "memory");
      __builtin_amdgcn_sched_barrier(0);   // rule#18 hygiene
      *(u32x4*)&hb[b0 * 1032 + cg0] = r0;
      *(u32x4*)&hb[b1 * 1032 + cg1] = r1;
    }

    // prefetch this step's x_proj scalars (gates threads only; comb stride 4096)
    float xr = 0.f, xz = 0.f, xn = 0.f;
    if (tid < 256){
      const float* xp = xproj + ((size_t)(bb << 8) + s) * 4096;
      xr = xp[j0 + jj]; xz = xp[1024 + j0 + jj]; xn = xp[2048 + j0 + jj];
    }
    __syncthreads();

    // ---- MFMA: wave wid<12 = (gate wid>>2, K-quarter wid&3) ----
    if (wid < 12){
      const int gate = wid >> 2, Koff = (wid & 3) * 256;
      f32x4 acc0 = {0.f, 0.f, 0.f, 0.f};
      f32x4 acc1 = {0.f, 0.f, 0.f, 0.f};
      const u16* wrow = &Wl[(gate * 16 + l15) * 1032 + Koff];
      const u16* hrow = &hb[l15 * 1032 + Koff];
      #pragma unroll
      for (int kk = 0; kk < 256; kk += 64){
        bf16x8 a0 = *(const bf16x8*)&hrow[kk + kh8];
        bf16x8 w0 = *(const bf16x8*)&wrow[kk + kh8];
        acc0 = __builtin_amdgcn_mfma_f32_16x16x32_bf16(a0, w0, acc0, 0, 0, 0);
        bf16x8 a1 = *(const bf16x8*)&hrow[kk + 32 + kh8];
        bf16x8 w1 = *(const bf16x8*)&wrow[kk + 32 + kh8];
        acc1 = __builtin_amdgcn_mfma_f32_16x16x32_bf16(a1, w1, acc1, 0, 0, 0);
      }
      #pragma unroll
      for (int i = 0; i < 4; ++i)
        gbuf[wid * 256 + ((lane >> 4) * 4 + i) * 16 + l15] = acc0[i] + acc1[i];
    }
    __syncthreads();

    // ---- gates (tid<256): sum 4 K-quarter partials per gate; publish ----
    if (tid < 256){
      int ic = bb * 16 + jj;
      float hr = gbuf[0 * 256 + ic] + gbuf[1 * 256 + ic] +
                 gbuf[2 * 256 + ic] + gbuf[3 * 256 + ic] + bh0;
      float hz = gbuf[4 * 256 + ic] + gbuf[5 * 256 + ic] +
                 gbuf[6 * 256 + ic] + gbuf[7 * 256 + ic] + bh1;
      float hn = gbuf[8 * 256 + ic] + gbuf[9 * 256 + ic] +
                 gbuf[10 * 256 + ic] + gbuf[11 * 256 + ic] + bh2;
      float r = 1.f / (1.f + __expf(-(xr + hr)));
      float z = 1.f / (1.f + __expf(-(xz + hz)));
      float nn = tanhf(xn + r * hn);
      float hnew = (1.f - z) * nn + z * hown[bb * 16 + jj];
      hown[bb * 16 + jj] = hnew;
      float hnext = __shfl_down(hnew, 1);
      if ((jj & 1) == 0){
        u32 pack = (u32)f2bf(hnew) | ((u32)f2bf(hnext) << 16);
        size_t e = (size_t)((bb << 8) + s) * 1024 + j0 + jj;
        __hip_atomic_store(&hs32[e >> 1], pack, __ATOMIC_RELAXED,
                           __HIP_MEMORY_SCOPE_AGENT);
      }
    }

    if (s < 255){
      asm volatile("s_waitcnt vmcnt(0)" ::: "memory");
      __syncthreads();
      if (tid == 0)
        __hip_atomic_store(&flags[g * 32], s + 1, __ATOMIC_RELAXED,
                           __HIP_MEMORY_SCOPE_AGENT);
      if (wid == 0){
        while (__hip_atomic_load(&flags[lane * 32], __ATOMIC_RELAXED,
                                 __HIP_MEMORY_SCOPE_AGENT) <= s)
          __builtin_amdgcn_s_sleep(1);
      }
      __syncthreads();
    }
  }
}

extern "C" void kernel_launch(void* const* d_in, const int* in_sizes, int n_in,
                              void* d_out, int out_size, void* d_ws, size_t ws_size,
                              hipStream_t stream)
{
  const float* ctx    = (const float*)d_in[0];
  const int*   target = (const int*)d_in[1];
  const float* embed  = (const float*)d_in[2];
  const float* Ws2d   = (const float*)d_in[3];
  const float* bs2d   = (const float*)d_in[4];
  const float* Wdec   = (const float*)d_in[5];
  const float* Wses   = (const float*)d_in[6];
  const float* Wemb   = (const float*)d_in[7];
  const float* bemb   = (const float*)d_in[8];
  const float* Wih    = (const float*)d_in[9];
  const float* Whh    = (const float*)d_in[10];
  const float* bih    = (const float*)d_in[11];
  const float* bhh    = (const float*)d_in[12];
  float* out = (float*)d_out;

  char* ws = (char*)d_ws;
  size_t off = 0;
  auto alloc = [&](size_t bytes)->char*{
    char* p = ws + off; off += (bytes + 255) & ~(size_t)255; return p;
  };
  u16*   embedBF = (u16*)alloc(32000ull * 512 * 2);
  u16*   WihBF   = (u16*)alloc(3072ull * 512 * 2);   // contiguous with WembBF:
  u16*   WembBF  = (u16*)alloc(1024ull * 512 * 2);   // combined B = [Wih; Wemb]
  u16*   WdecBF  = (u16*)alloc(1024ull * 1024 * 2);
  u16*   WhhBF   = (u16*)alloc(3072ull * 1024 * 2);
  u16*   embBF   = (u16*)alloc(4096ull * 512 * 2);
  float* comb    = (float*)alloc(4096ull * 4096 * 4); // [xproj(3072) | embinf(1024)]
  float* sesinf  = (float*)alloc(16ull * 1024 * 4);
  float* h0f     = (float*)alloc(16ull * 1024 * 4);
  u16*   h0bf    = (u16*)alloc(16ull * 1024 * 2);
  u16*   hsBF    = (u16*)alloc(4096ull * 1024 * 2);
  u16*   mxBF    = (u16*)alloc(4096ull * 512 * 2);
  int*   flags   = (int*)alloc(16384);
  (void)ws_size; (void)in_sizes; (void)n_in; (void)out_size;

  hipFuncSetAttribute((const void*)gru_kernel,
                      hipFuncAttributeMaxDynamicSharedMemorySize, GRU_LDS);
  hipMemsetAsync(flags, 0, 16384, stream);

  // fused: weight conversion (11072 blocks) + ctx projections (8192 blocks)
  fused_pre_kernel<<<19264, 256, 0, stream>>>(
      embed, Wih, Wemb, Wdec, Whh,
      embedBF, WihBF, WembBF, WdecBF, WhhBF,
      ctx, Wses, Ws2d, bs2d, sesinf, h0f, h0bf);

  gather_kernel<<<4096, 64, 0, stream>>>(target, embedBF, embBF);

  // combined pre-GEMM: [x_proj | emb_inf] = emb @ [Wih;Wemb]^T + [bih;bemb]
  gemm_bt<5,0><<<dim3(4096 / 128, 4096 / 128), 256, 0, stream>>>(
      embBF, WihBF, comb, 4096, 4096, 512, bih, bemb, nullptr, nullptr, 0, nullptr);

  gru_kernel<<<GRU_NWG, 1024, GRU_LDS, stream>>>(WhhBF, bhh, comb, h0f, h0bf,
                                                 hsBF, flags);

  // total = hs @ W_dec^T + ses_inf[b] + emb_inf(comb+3072) ; fused maxout -> mxBF
  gemm_bt<3,0><<<dim3(1024 / 128, 4096 / 128), 256, 0, stream>>>(
      hsBF, WdecBF, nullptr, 4096, 1024, 1024, nullptr, nullptr,
      sesinf, comb + 3072, 4096, mxBF);

  // logits = mx @ embed^T  (XCD-swizzled: 8000 WGs % 8 == 0)
  gemm_bt<0,1><<<dim3(32000 / 128, 4096 / 128), 256, 0, stream>>>(
      mxBF, embedBF, out, 4096, 32000, 512, nullptr, nullptr,
      nullptr, nullptr, 0, nullptr);
}